// Round 7
// baseline (328.553 us; speedup 1.0000x reference)
//
#include <hip/hip_runtime.h>
#include <math.h>

#define BATCH 2
#define SLEN  2048
#define HIDD  1024
#define NHEAD 16
#define DHEAD 64
#define NEGV  (-1e-09f)   // faithful to source: tiny negative, NOT -1e9

typedef __attribute__((ext_vector_type(8))) short bf16x8;
typedef __attribute__((ext_vector_type(4))) float f32x4;
typedef unsigned short u16;
typedef unsigned long long u64;

// RTNE float -> bf16 bits (inputs finite)
__device__ __forceinline__ u16 f2bf(float x) {
    unsigned u = __builtin_bit_cast(unsigned, x);
    return (u16)((u + 0x7fffu + ((u >> 16) & 1u)) >> 16);
}

// async global->LDS, 16B per lane (m97 pattern: LDS dest = wave base + lane*16)
#define GLD16(gp, lp) __builtin_amdgcn_global_load_lds(                      \
    (__attribute__((address_space(1))) void*)(gp),                           \
    (__attribute__((address_space(3))) void*)(lp), 16, 0, 0)

// ---------------------------------------------------------------------------
// fp32 -> bf16 conversion pre-pass. z: 0..2 = Q,K,V (4.19M), 3..6 = W* (1.05M)
// ---------------------------------------------------------------------------
__global__ __launch_bounds__(256) void cvt_kernel(
    const float* __restrict__ s0, const float* __restrict__ s1,
    const float* __restrict__ s2, const float* __restrict__ s3,
    const float* __restrict__ s4, const float* __restrict__ s5,
    const float* __restrict__ s6,
    u16* __restrict__ d0, u16* __restrict__ d1, u16* __restrict__ d2,
    u16* __restrict__ d3, u16* __restrict__ d4, u16* __restrict__ d5,
    u16* __restrict__ d6)
{
    const float* sp; u16* dp; int n;
    switch (blockIdx.z) {
        case 0: sp = s0; dp = d0; n = 4194304; break;
        case 1: sp = s1; dp = d1; n = 4194304; break;
        case 2: sp = s2; dp = d2; n = 4194304; break;
        case 3: sp = s3; dp = d3; n = 1048576; break;
        case 4: sp = s4; dp = d4; n = 1048576; break;
        case 5: sp = s5; dp = d5; n = 1048576; break;
        default: sp = s6; dp = d6; n = 1048576; break;
    }
    const int idx = (blockIdx.x * 256 + threadIdx.x) * 8;
    if (idx >= n) return;
    const float4 a = *(const float4*)(sp + idx);
    const float4 c = *(const float4*)(sp + idx + 4);
    union { bf16x8 v; u16 u[8]; } o;
    o.u[0] = f2bf(a.x); o.u[1] = f2bf(a.y); o.u[2] = f2bf(a.z); o.u[3] = f2bf(a.w);
    o.u[4] = f2bf(c.x); o.u[5] = f2bf(c.y); o.u[6] = f2bf(c.z); o.u[7] = f2bf(c.w);
    *(bf16x8*)(dp + idx) = o.v;
}

// ---------------------------------------------------------------------------
// bf16 MFMA GEMM, m97 structure: 128x128 tile, BK=32, global_load_lds w=16,
// linear LDS [128 rows][32 k] bf16, 4 waves (2x2), 16x16x32 MFMA, 4x4 frags.
// Delivers bit-identical operands to the verified reg-staged round-2 GEMM —
// only the LDS transport differs. MODE 0: bf16 head-split out. MODE 1: fp32.
// ---------------------------------------------------------------------------
template<int MODE>
__device__ __forceinline__ void gemm128(const u16* __restrict__ A,
                                        const u16* __restrict__ W,
                                        const float* __restrict__ bias,
                                        void* __restrict__ outp)
{
    __shared__ __align__(16) u16 sA[4096];   // [128][32] bf16, 8KB, linear
    __shared__ __align__(16) u16 sB[4096];
    const int t  = threadIdx.x;
    const int l  = t & 63, w = t >> 6;
    const int wr = w >> 1, wc = w & 1;
    const int m0 = blockIdx.y * 128, n0 = blockIdx.x * 128;

    f32x4 acc[4][4];
#pragma unroll
    for (int i = 0; i < 4; ++i)
#pragma unroll
        for (int j = 0; j < 4; ++j) acc[i][j] = (f32x4){0.f, 0.f, 0.f, 0.f};

    // staging map: thread t -> row t/4 (+64 on 2nd issue), 16B chunk t%4.
    // LDS byte t*16 == row*64 + chunk*16 -> linear, matches HW lane order
    // (wave base w*1024 + lane*16).
    const int srow = t >> 2;
    const int scol = (t & 3) * 8;            // u16 units
    const u16* Ap = A + (size_t)(m0 + srow) * HIDD + scol;
    const u16* Wp = W + (size_t)(n0 + srow) * HIDD + scol;

    for (int k0 = 0; k0 < HIDD; k0 += 32) {
        __syncthreads();                     // all frag reads of prev tile done
        GLD16(Ap + k0,                      &sA[t * 8]);
        GLD16(Ap + k0 + (size_t)64 * HIDD,  &sA[2048 + t * 8]);
        GLD16(Wp + k0,                      &sB[t * 8]);
        GLD16(Wp + k0 + (size_t)64 * HIDD,  &sB[2048 + t * 8]);
        __syncthreads();                     // vmcnt(0) drain -> LDS ready

        bf16x8 af[4], bg[4];
#pragma unroll
        for (int i = 0; i < 4; ++i) {
            af[i] = *(const bf16x8*)&sA[(wr * 64 + i * 16 + (l & 15)) * 32 + (l >> 4) * 8];
            bg[i] = *(const bf16x8*)&sB[(wc * 64 + i * 16 + (l & 15)) * 32 + (l >> 4) * 8];
        }
#pragma unroll
        for (int mi = 0; mi < 4; ++mi)
#pragma unroll
            for (int ni = 0; ni < 4; ++ni)
                acc[mi][ni] = __builtin_amdgcn_mfma_f32_16x16x32_bf16(
                                  af[mi], bg[ni], acc[mi][ni], 0, 0, 0);
    }

    float bb[4];
#pragma unroll
    for (int ni = 0; ni < 4; ++ni) bb[ni] = bias[n0 + wc * 64 + ni * 16 + (l & 15)];

#pragma unroll
    for (int mi = 0; mi < 4; ++mi) {
#pragma unroll
        for (int ni = 0; ni < 4; ++ni) {
            const int n = n0 + wc * 64 + ni * 16 + (l & 15);
#pragma unroll
            for (int r = 0; r < 4; ++r) {
                const int m = m0 + wr * 64 + mi * 16 + (l >> 4) * 4 + r;
                const float v = acc[mi][ni][r] + bb[ni];
                if (MODE == 0) {   // bf16, [B,NH,S,DH]
                    const int b = m >> 11, s = m & (SLEN - 1);
                    const int h = n >> 6,  d = n & (DHEAD - 1);
                    ((u16*)outp)[(((size_t)(b * NHEAD + h)) * SLEN + s) * DHEAD + d] = f2bf(v);
                } else {           // fp32, [M][N]
                    ((float*)outp)[(size_t)m * HIDD + n] = v;
                }
            }
        }
    }
}

__global__ __launch_bounds__(256) void qkv_kernel(
    const u16* __restrict__ Qb, const u16* __restrict__ Kb, const u16* __restrict__ Vb,
    const u16* __restrict__ Wqb, const u16* __restrict__ Wkb, const u16* __restrict__ Wvb,
    const float* __restrict__ bq, const float* __restrict__ bk, const float* __restrict__ bv,
    u16* __restrict__ qh, u16* __restrict__ kh, u16* __restrict__ vh)
{
    if (blockIdx.z == 0)      gemm128<0>(Qb, Wqb, bq, qh);
    else if (blockIdx.z == 1) gemm128<0>(Kb, Wkb, bk, kh);
    else                      gemm128<0>(Vb, Wvb, bv, vh);
}

__global__ __launch_bounds__(256) void outproj_kernel(
    const u16* __restrict__ Cb, const u16* __restrict__ Wob,
    const float* __restrict__ bo, float* __restrict__ out)
{
    gemm128<1>(Cb, Wob, bo, out);
}

// ---------------------------------------------------------------------------
// V transpose: vh [B,NH,S,DH] -> vt [B,NH,DH,S]   (verbatim round-2 verified)
// ---------------------------------------------------------------------------
__global__ __launch_bounds__(256) void vtrans_kernel(const u16* __restrict__ vh,
                                                     u16* __restrict__ vt)
{
    const int bh = blockIdx.y, st = blockIdx.x, t = threadIdx.x;
    const u16* src = vh + ((size_t)bh * SLEN + st * 64) * DHEAD;
    u16* dst = vt + (size_t)bh * DHEAD * SLEN + st * 64;
    __shared__ u16 Ts[64][72];
#pragma unroll
    for (int it = 0; it < 2; ++it) {
        const int slot = t + it * 256;
        const int s = slot >> 3, c = (slot & 7) * 8;
        union { bf16x8 v; u16 u[8]; } x;
        x.v = *(const bf16x8*)(src + s * DHEAD + c);
#pragma unroll
        for (int j = 0; j < 8; ++j) Ts[c + j][s] = x.u[j];
    }
    __syncthreads();
#pragma unroll
    for (int it = 0; it < 2; ++it) {
        const int slot = t + it * 256;
        const int d = slot >> 3, c = (slot & 7) * 8;
        union { bf16x8 v; u16 u[8]; } x;
#pragma unroll
        for (int j = 0; j < 8; ++j) x.u[j] = Ts[d][c + j];
        *(bf16x8*)(dst + (size_t)d * SLEN + c) = x.v;
    }
}

// ---------------------------------------------------------------------------
// Mask bit-compaction: mb[b][s][c] (u64) — bit j = (padq*padk*am != 0)
// (verbatim round-2 verified)
// ---------------------------------------------------------------------------
__global__ __launch_bounds__(256) void mask_kernel(const float* __restrict__ pad,
                                                   const float* __restrict__ am,
                                                   u64* __restrict__ mb)
{
    const int gid = blockIdx.x * 256 + threadIdx.x;   // 131072
    const int c = gid & 31;
    const int s = (gid >> 5) & (SLEN - 1);
    const int b = gid >> 16;
    const float padq = pad[b * SLEN + s];
    const float* amrow = am + (size_t)s * SLEN + c * 64;
    const float* pkp   = pad + b * SLEN + c * 64;
    u64 bits = 0;
#pragma unroll
    for (int j0 = 0; j0 < 64; j0 += 4) {
        const float4 a  = *(const float4*)(amrow + j0);
        const float4 pk = *(const float4*)(pkp + j0);
        if (padq * pk.x * a.x != 0.f) bits |= (1ull << (j0 + 0));
        if (padq * pk.y * a.y != 0.f) bits |= (1ull << (j0 + 1));
        if (padq * pk.z * a.z != 0.f) bits |= (1ull << (j0 + 2));
        if (padq * pk.w * a.w != 0.f) bits |= (1ull << (j0 + 3));
    }
    mb[((size_t)b * SLEN + s) * 32 + c] = bits;
}

// ---------------------------------------------------------------------------
// Flash attention, bf16 MFMA — VERBATIM round-2 verified kernel (no skip,
// no setprio, 3 barriers/iter). Block = (qt, h, b), 4 waves.
// ---------------------------------------------------------------------------
__global__ __launch_bounds__(256) void flash_kernel(
    const u16* __restrict__ qh, const u16* __restrict__ kh,
    const u16* __restrict__ vt, const u64* __restrict__ mb,
    u16* __restrict__ cb)
{
    __shared__ __align__(16) char smem[24576];  // K 8KB | Vt 8KB | P 4x2KB
    const int qt = blockIdx.x, h = blockIdx.y, b = blockIdx.z;
    const int t = threadIdx.x, l = t & 63, w = t >> 6;
    const int head = b * NHEAD + h;
    const u16* qp = qh + ((size_t)head * SLEN + qt * 64) * DHEAD;
    const u16* kp = kh + (size_t)head * SLEN * DHEAD;
    const u16* vp = vt + (size_t)head * DHEAD * SLEN;

    bf16x8 qf[2];
#pragma unroll
    for (int ks = 0; ks < 2; ++ks)
        qf[ks] = *(const bf16x8*)(qp + (w * 16 + (l & 15)) * DHEAD
                                     + ks * 32 + (l >> 4) * 8);

    f32x4 oacc[4];
    float mrun[4], lrun[4];
#pragma unroll
    for (int i = 0; i < 4; ++i) {
        oacc[i] = (f32x4){0.f, 0.f, 0.f, 0.f};
        mrun[i] = -INFINITY; lrun[i] = 0.f;
    }

    const int scb = (t & 7) * 16;     // staging col-byte within 128B row

    for (int kt = 0; kt < SLEN / 64; ++kt) {
        bf16x8 kv[2], vv[2];
#pragma unroll
        for (int it = 0; it < 2; ++it) {
            const int row = (t >> 3) + it * 32;
            kv[it] = *(const bf16x8*)(kp + ((size_t)(kt * 64 + row)) * DHEAD + scb / 2);
            vv[it] = *(const bf16x8*)(vp + (size_t)row * SLEN + kt * 64 + scb / 2);
        }
        __syncthreads();              // previous iteration's LDS reads done
#pragma unroll
        for (int it = 0; it < 2; ++it) {
            const int row  = (t >> 3) + it * 32;
            const int byte = row * 128 + (scb ^ ((row & 7) << 4));
            *(bf16x8*)(smem + byte)        = kv[it];
            *(bf16x8*)(smem + 8192 + byte) = vv[it];
        }
        __syncthreads();

        // ---- S = Q K^T (per wave: 16 q-rows x 64 kpos) ----
        f32x4 s4[4];
#pragma unroll
        for (int nf = 0; nf < 4; ++nf) s4[nf] = (f32x4){0.f, 0.f, 0.f, 0.f};
#pragma unroll
        for (int ks = 0; ks < 2; ++ks) {
#pragma unroll
            for (int nf = 0; nf < 4; ++nf) {
                const int kr = nf * 16 + (l & 15);
                const bf16x8 kf = *(const bf16x8*)(smem + kr * 128 +
                        ((ks * 64 + (l >> 4) * 16) ^ ((kr & 7) << 4)));
                s4[nf] = __builtin_amdgcn_mfma_f32_16x16x32_bf16(qf[ks], kf, s4[nf], 0, 0, 0);
            }
        }

        // ---- mask + online softmax ----
        const int rbase = qt * 64 + w * 16 + (l >> 4) * 4;
        u64 bits[4];
#pragma unroll
        for (int r = 0; r < 4; ++r)
            bits[r] = mb[((size_t)b * SLEN + rbase + r) * 32 + kt];
#pragma unroll
        for (int r = 0; r < 4; ++r) {
            float sv[4];
#pragma unroll
            for (int nf = 0; nf < 4; ++nf) {
                const int bit = nf * 16 + (l & 15);
                sv[nf] = ((bits[r] >> bit) & 1ull) ? s4[nf][r] * 0.125f : NEGV;
            }
            float rm = fmaxf(fmaxf(sv[0], sv[1]), fmaxf(sv[2], sv[3]));
            rm = fmaxf(rm, __shfl_xor(rm, 1));
            rm = fmaxf(rm, __shfl_xor(rm, 2));
            rm = fmaxf(rm, __shfl_xor(rm, 4));
            rm = fmaxf(rm, __shfl_xor(rm, 8));
            const float mnew = fmaxf(mrun[r], rm);
            const float corr = __expf(mrun[r] - mnew);   // exp(-inf)=0 on iter 0
            float p[4], rs = 0.f;
#pragma unroll
            for (int nf = 0; nf < 4; ++nf) { p[nf] = __expf(sv[nf] - mnew); rs += p[nf]; }
            rs += __shfl_xor(rs, 1);
            rs += __shfl_xor(rs, 2);
            rs += __shfl_xor(rs, 4);
            rs += __shfl_xor(rs, 8);
            lrun[r] = lrun[r] * corr + rs;
            mrun[r] = mnew;
#pragma unroll
            for (int nf = 0; nf < 4; ++nf) oacc[nf][r] *= corr;
            const int prow = (l >> 4) * 4 + r;
#pragma unroll
            for (int nf = 0; nf < 4; ++nf) {
                const int col = nf * 16 + (l & 15);
                *(u16*)(smem + 16384 + w * 2048 + prow * 128 +
                        ((col * 2) ^ ((prow & 7) << 4))) = f2bf(p[nf]);
            }
        }

        // ---- ctx += P V ----
#pragma unroll
        for (int ks = 0; ks < 2; ++ks) {
            const bf16x8 pf = *(const bf16x8*)(smem + 16384 + w * 2048 + (l & 15) * 128 +
                    ((ks * 64 + (l >> 4) * 16) ^ ((l & 7) << 4)));
#pragma unroll
            for (int nf = 0; nf < 4; ++nf) {
                const int vr = nf * 16 + (l & 15);
                const bf16x8 vf = *(const bf16x8*)(smem + 8192 + vr * 128 +
                        ((ks * 64 + (l >> 4) * 16) ^ ((vr & 7) << 4)));
                oacc[nf] = __builtin_amdgcn_mfma_f32_16x16x32_bf16(pf, vf, oacc[nf], 0, 0, 0);
            }
        }
        __syncthreads();              // all waves done before next staging
    }

    // ---- epilogue: ctx bf16, merged [B*S][HID] layout ----
#pragma unroll
    for (int r = 0; r < 4; ++r) {
        const float inv = 1.f / lrun[r];
        const int srow = qt * 64 + w * 16 + (l >> 4) * 4 + r;
#pragma unroll
        for (int nf = 0; nf < 4; ++nf) {
            const float v = oacc[nf][r] * inv;
            cb[((size_t)b * SLEN + srow) * HIDD + h * DHEAD + nf * 16 + (l & 15)] = f2bf(v);
        }
    }
}

// ---------------------------------------------------------------------------
extern "C" void kernel_launch(void* const* d_in, const int* in_sizes, int n_in,
                              void* d_out, int out_size, void* d_ws, size_t ws_size,
                              hipStream_t stream)
{
    (void)in_sizes; (void)n_in; (void)out_size; (void)ws_size;
    const float* Q   = (const float*)d_in[0];
    const float* K   = (const float*)d_in[1];
    const float* V   = (const float*)d_in[2];
    const float* pad = (const float*)d_in[3];
    const float* am  = (const float*)d_in[4];
    const float* Wq  = (const float*)d_in[5];
    const float* bq  = (const float*)d_in[6];
    const float* Wk  = (const float*)d_in[7];
    const float* bk  = (const float*)d_in[8];
    const float* Wv  = (const float*)d_in[9];
    const float* bv  = (const float*)d_in[10];
    const float* Wo  = (const float*)d_in[11];
    const float* bo  = (const float*)d_in[12];
    float* out = (float*)d_out;

    char* ws = (char*)d_ws;
    const size_t MB = 1u << 20;
    u16* Qb  = (u16*)(ws + 0);        // 8MB (reused as cb after qkv)
    u16* Kb  = (u16*)(ws + 8  * MB);  // 8MB
    u16* Vb  = (u16*)(ws + 16 * MB);  // 8MB
    u16* Wqb = (u16*)(ws + 24 * MB);  // 2MB
    u16* Wkb = (u16*)(ws + 26 * MB);  // 2MB
    u16* Wvb = (u16*)(ws + 28 * MB);  // 2MB
    u16* Wob = (u16*)(ws + 30 * MB);  // 2MB
    u16* qhp = (u16*)(ws + 32 * MB);  // 8MB [B,NH,S,DH]
    u16* khp = (u16*)(ws + 40 * MB);  // 8MB
    u16* vhp = (u16*)(ws + 48 * MB);  // 8MB
    u16* vtp = (u16*)(ws + 56 * MB);  // 8MB [B,NH,DH,S]
    u64* mbp = (u64*)(ws + 64 * MB);  // 1MB mask bits
    u16* cbp = (u16*)(ws + 0);        // ctx bf16, aliases Qb (dead by then)

    cvt_kernel<<<dim3(2048, 1, 7), 256, 0, stream>>>(Q, K, V, Wq, Wk, Wv, Wo,
                                                     Qb, Kb, Vb, Wqb, Wkb, Wvb, Wob);
    qkv_kernel<<<dim3(8, 32, 3), 256, 0, stream>>>(Qb, Kb, Vb, Wqb, Wkb, Wvb,
                                                   bq, bk, bv, qhp, khp, vhp);
    vtrans_kernel<<<dim3(32, 32), 256, 0, stream>>>(vhp, vtp);
    mask_kernel<<<dim3(512), 256, 0, stream>>>(pad, am, mbp);
    flash_kernel<<<dim3(32, 16, 2), 256, 0, stream>>>(qhp, khp, vtp, mbp, cbp);
    outproj_kernel<<<dim3(8, 32, 1), 256, 0, stream>>>(cbp, Wob, bo, out);
}

// Round 8
// 313.270 us; speedup vs baseline: 1.0488x; 1.0488x over previous
//
#include <hip/hip_runtime.h>
#include <math.h>

#define BATCH 2
#define SLEN  2048
#define HIDD  1024
#define NHEAD 16
#define DHEAD 64
#define NEGV  (-1e-09f)   // faithful to source: tiny negative, NOT -1e9

typedef __attribute__((ext_vector_type(8))) short bf16x8;
typedef __attribute__((ext_vector_type(4))) float f32x4;
typedef unsigned short u16;
typedef unsigned long long u64;

// RTNE float -> bf16 bits (inputs finite)
__device__ __forceinline__ u16 f2bf(float x) {
    unsigned u = __builtin_bit_cast(unsigned, x);
    return (u16)((u + 0x7fffu + ((u >> 16) & 1u)) >> 16);
}

// async global->LDS, 16B per lane (m97 pattern: LDS dest = wave base + lane*16)
#define GLD16(gp, lp) __builtin_amdgcn_global_load_lds(                      \
    (__attribute__((address_space(1))) void*)(gp),                           \
    (__attribute__((address_space(3))) void*)(lp), 16, 0, 0)

// ---------------------------------------------------------------------------
// fp32 -> bf16 conversion pre-pass. z: 0..2 = Q,K,V (4.19M), 3..6 = W* (1.05M)
// ---------------------------------------------------------------------------
__global__ __launch_bounds__(256) void cvt_kernel(
    const float* __restrict__ s0, const float* __restrict__ s1,
    const float* __restrict__ s2, const float* __restrict__ s3,
    const float* __restrict__ s4, const float* __restrict__ s5,
    const float* __restrict__ s6,
    u16* __restrict__ d0, u16* __restrict__ d1, u16* __restrict__ d2,
    u16* __restrict__ d3, u16* __restrict__ d4, u16* __restrict__ d5,
    u16* __restrict__ d6)
{
    const float* sp; u16* dp; int n;
    switch (blockIdx.z) {
        case 0: sp = s0; dp = d0; n = 4194304; break;
        case 1: sp = s1; dp = d1; n = 4194304; break;
        case 2: sp = s2; dp = d2; n = 4194304; break;
        case 3: sp = s3; dp = d3; n = 1048576; break;
        case 4: sp = s4; dp = d4; n = 1048576; break;
        case 5: sp = s5; dp = d5; n = 1048576; break;
        default: sp = s6; dp = d6; n = 1048576; break;
    }
    const int idx = (blockIdx.x * 256 + threadIdx.x) * 8;
    if (idx >= n) return;
    const float4 a = *(const float4*)(sp + idx);
    const float4 c = *(const float4*)(sp + idx + 4);
    union { bf16x8 v; u16 u[8]; } o;
    o.u[0] = f2bf(a.x); o.u[1] = f2bf(a.y); o.u[2] = f2bf(a.z); o.u[3] = f2bf(a.w);
    o.u[4] = f2bf(c.x); o.u[5] = f2bf(c.y); o.u[6] = f2bf(c.z); o.u[7] = f2bf(c.w);
    *(bf16x8*)(dp + idx) = o.v;
}

// ---------------------------------------------------------------------------
// bf16 MFMA GEMM, m97 structure (VERIFIED round 7): 128x128 tile, BK=32,
// global_load_lds w=16, linear LDS, 4 waves (2x2), 16x16x32 MFMA.
// MODE 0: bf16 out in [B,NH,S,DH] head-split layout. MODE 1: fp32 flat.
// ---------------------------------------------------------------------------
template<int MODE>
__device__ __forceinline__ void gemm128(const u16* __restrict__ A,
                                        const u16* __restrict__ W,
                                        const float* __restrict__ bias,
                                        void* __restrict__ outp)
{
    __shared__ __align__(16) u16 sA[4096];   // [128][32] bf16, 8KB, linear
    __shared__ __align__(16) u16 sB[4096];
    const int t  = threadIdx.x;
    const int l  = t & 63, w = t >> 6;
    const int wr = w >> 1, wc = w & 1;
    const int m0 = blockIdx.y * 128, n0 = blockIdx.x * 128;

    f32x4 acc[4][4];
#pragma unroll
    for (int i = 0; i < 4; ++i)
#pragma unroll
        for (int j = 0; j < 4; ++j) acc[i][j] = (f32x4){0.f, 0.f, 0.f, 0.f};

    const int srow = t >> 2;
    const int scol = (t & 3) * 8;            // u16 units
    const u16* Ap = A + (size_t)(m0 + srow) * HIDD + scol;
    const u16* Wp = W + (size_t)(n0 + srow) * HIDD + scol;

    for (int k0 = 0; k0 < HIDD; k0 += 32) {
        __syncthreads();                     // all frag reads of prev tile done
        GLD16(Ap + k0,                      &sA[t * 8]);
        GLD16(Ap + k0 + (size_t)64 * HIDD,  &sA[2048 + t * 8]);
        GLD16(Wp + k0,                      &sB[t * 8]);
        GLD16(Wp + k0 + (size_t)64 * HIDD,  &sB[2048 + t * 8]);
        __syncthreads();                     // vmcnt(0) drain -> LDS ready

        bf16x8 af[4], bg[4];
#pragma unroll
        for (int i = 0; i < 4; ++i) {
            af[i] = *(const bf16x8*)&sA[(wr * 64 + i * 16 + (l & 15)) * 32 + (l >> 4) * 8];
            bg[i] = *(const bf16x8*)&sB[(wc * 64 + i * 16 + (l & 15)) * 32 + (l >> 4) * 8];
        }
#pragma unroll
        for (int mi = 0; mi < 4; ++mi)
#pragma unroll
            for (int ni = 0; ni < 4; ++ni)
                acc[mi][ni] = __builtin_amdgcn_mfma_f32_16x16x32_bf16(
                                  af[mi], bg[ni], acc[mi][ni], 0, 0, 0);
    }

    float bb[4];
#pragma unroll
    for (int ni = 0; ni < 4; ++ni) bb[ni] = bias[n0 + wc * 64 + ni * 16 + (l & 15)];

#pragma unroll
    for (int mi = 0; mi < 4; ++mi) {
#pragma unroll
        for (int ni = 0; ni < 4; ++ni) {
            const int n = n0 + wc * 64 + ni * 16 + (l & 15);
#pragma unroll
            for (int r = 0; r < 4; ++r) {
                const int m = m0 + wr * 64 + mi * 16 + (l >> 4) * 4 + r;
                const float v = acc[mi][ni][r] + bb[ni];
                if (MODE == 0) {   // bf16, [B,NH,S,DH]
                    const int b = m >> 11, s = m & (SLEN - 1);
                    const int h = n >> 6,  d = n & (DHEAD - 1);
                    ((u16*)outp)[(((size_t)(b * NHEAD + h)) * SLEN + s) * DHEAD + d] = f2bf(v);
                } else {           // fp32, [M][N]
                    ((float*)outp)[(size_t)m * HIDD + n] = v;
                }
            }
        }
    }
}

__global__ __launch_bounds__(256) void qkv_kernel(
    const u16* __restrict__ Qb, const u16* __restrict__ Kb, const u16* __restrict__ Vb,
    const u16* __restrict__ Wqb, const u16* __restrict__ Wkb, const u16* __restrict__ Wvb,
    const float* __restrict__ bq, const float* __restrict__ bk, const float* __restrict__ bv,
    u16* __restrict__ qh, u16* __restrict__ kh, u16* __restrict__ vh)
{
    if (blockIdx.z == 0)      gemm128<0>(Qb, Wqb, bq, qh);
    else if (blockIdx.z == 1) gemm128<0>(Kb, Wkb, bk, kh);
    else                      gemm128<0>(Vb, Wvb, bv, vh);
}

__global__ __launch_bounds__(256) void outproj_kernel(
    const u16* __restrict__ Cb, const u16* __restrict__ Wob,
    const float* __restrict__ bo, float* __restrict__ out)
{
    gemm128<1>(Cb, Wob, bo, out);
}

// ---------------------------------------------------------------------------
// V transpose: vh [B,NH,S,DH] -> vt [B,NH,DH,S]   (verbatim verified)
// ---------------------------------------------------------------------------
__global__ __launch_bounds__(256) void vtrans_kernel(const u16* __restrict__ vh,
                                                     u16* __restrict__ vt)
{
    const int bh = blockIdx.y, st = blockIdx.x, t = threadIdx.x;
    const u16* src = vh + ((size_t)bh * SLEN + st * 64) * DHEAD;
    u16* dst = vt + (size_t)bh * DHEAD * SLEN + st * 64;
    __shared__ u16 Ts[64][72];
#pragma unroll
    for (int it = 0; it < 2; ++it) {
        const int slot = t + it * 256;
        const int s = slot >> 3, c = (slot & 7) * 8;
        union { bf16x8 v; u16 u[8]; } x;
        x.v = *(const bf16x8*)(src + s * DHEAD + c);
#pragma unroll
        for (int j = 0; j < 8; ++j) Ts[c + j][s] = x.u[j];
    }
    __syncthreads();
#pragma unroll
    for (int it = 0; it < 2; ++it) {
        const int slot = t + it * 256;
        const int d = slot >> 3, c = (slot & 7) * 8;
        union { bf16x8 v; u16 u[8]; } x;
#pragma unroll
        for (int j = 0; j < 8; ++j) x.u[j] = Ts[d][c + j];
        *(bf16x8*)(dst + (size_t)d * SLEN + c) = x.v;
    }
}

// ---------------------------------------------------------------------------
// Mask bit-compaction: mb[b][s][c] (u64) — bit j = (padq*padk*am != 0)
// (verbatim verified)
// ---------------------------------------------------------------------------
__global__ __launch_bounds__(256) void mask_kernel(const float* __restrict__ pad,
                                                   const float* __restrict__ am,
                                                   u64* __restrict__ mb)
{
    const int gid = blockIdx.x * 256 + threadIdx.x;   // 131072
    const int c = gid & 31;
    const int s = (gid >> 5) & (SLEN - 1);
    const int b = gid >> 16;
    const float padq = pad[b * SLEN + s];
    const float* amrow = am + (size_t)s * SLEN + c * 64;
    const float* pkp   = pad + b * SLEN + c * 64;
    u64 bits = 0;
#pragma unroll
    for (int j0 = 0; j0 < 64; j0 += 4) {
        const float4 a  = *(const float4*)(amrow + j0);
        const float4 pk = *(const float4*)(pkp + j0);
        if (padq * pk.x * a.x != 0.f) bits |= (1ull << (j0 + 0));
        if (padq * pk.y * a.y != 0.f) bits |= (1ull << (j0 + 1));
        if (padq * pk.z * a.z != 0.f) bits |= (1ull << (j0 + 2));
        if (padq * pk.w * a.w != 0.f) bits |= (1ull << (j0 + 3));
    }
    mb[((size_t)b * SLEN + s) * 32 + c] = bits;
}

// ---------------------------------------------------------------------------
// Flash attention, bf16 MFMA, SWAPPED QK^T (S^T = mfma(K,Q)): each lane owns
// q-row q=l&15 -> softmax reduce = 15 fmax + 2 shfl (vs 16-wide x4 rows).
// kf/qf fragment reads are byte-identical to the verified kernel; only the
// mfma operand order changes. P store/PV/oacc layout unchanged. 2 barriers.
// ---------------------------------------------------------------------------
__global__ __launch_bounds__(256) void flash_kernel(
    const u16* __restrict__ qh, const u16* __restrict__ kh,
    const u16* __restrict__ vt, const u64* __restrict__ mb,
    u16* __restrict__ cb)
{
    __shared__ __align__(16) char smem[24576];  // K 8KB | Vt 8KB | P 4x2KB
    const int qt = blockIdx.x, h = blockIdx.y, b = blockIdx.z;
    const int t = threadIdx.x, l = t & 63, w = t >> 6;
    const int q = l & 15, hi = l >> 4;
    const int head = b * NHEAD + h;
    const u16* qp = qh + ((size_t)head * SLEN + qt * 64) * DHEAD;
    const u16* kp = kh + (size_t)head * SLEN * DHEAD;
    const u16* vp = vt + (size_t)head * DHEAD * SLEN;
    // per-lane mask row: q-row (qt*64 + w*16 + q), one u64 per 64-kpos tile
    const u64* mrow = mb + ((size_t)b * SLEN + qt * 64 + w * 16 + q) * 32;

    bf16x8 qf[2];
#pragma unroll
    for (int ks = 0; ks < 2; ++ks)
        qf[ks] = *(const bf16x8*)(qp + (w * 16 + q) * DHEAD + ks * 32 + hi * 8);

    f32x4 oacc[4];
#pragma unroll
    for (int i = 0; i < 4; ++i) oacc[i] = (f32x4){0.f, 0.f, 0.f, 0.f};
    float mq = -INFINITY, lq = 0.f;   // softmax state for this lane's q-row

    const int scb = (t & 7) * 16;     // staging col-byte within 128B row

    for (int kt = 0; kt < SLEN / 64; ++kt) {
        bf16x8 kv[2], vv[2];
#pragma unroll
        for (int it = 0; it < 2; ++it) {
            const int row = (t >> 3) + it * 32;
            kv[it] = *(const bf16x8*)(kp + ((size_t)(kt * 64 + row)) * DHEAD + scb / 2);
            vv[it] = *(const bf16x8*)(vp + (size_t)row * SLEN + kt * 64 + scb / 2);
        }
        __syncthreads();              // prev iter's LDS reads done (incl. PV)
#pragma unroll
        for (int it = 0; it < 2; ++it) {
            const int row  = (t >> 3) + it * 32;
            const int byte = row * 128 + (scb ^ ((row & 7) << 4));
            *(bf16x8*)(smem + byte)        = kv[it];
            *(bf16x8*)(smem + 8192 + byte) = vv[it];
        }
        __syncthreads();

        // ---- S^T = K Q^T : lane holds S[kpos=nf*16+hi*4+r][qrow=q] ----
        f32x4 s4t[4];
#pragma unroll
        for (int nf = 0; nf < 4; ++nf) s4t[nf] = (f32x4){0.f, 0.f, 0.f, 0.f};
#pragma unroll
        for (int ks = 0; ks < 2; ++ks) {
#pragma unroll
            for (int nf = 0; nf < 4; ++nf) {
                const int kr = nf * 16 + q;
                const bf16x8 kf = *(const bf16x8*)(smem + kr * 128 +
                        ((ks * 64 + hi * 16) ^ ((kr & 7) << 4)));
                s4t[nf] = __builtin_amdgcn_mfma_f32_16x16x32_bf16(kf, qf[ks], s4t[nf], 0, 0, 0);
            }
        }

        // ---- mask + online softmax (lane-local row) ----
        const u64 bits = mrow[kt];
        float p[4][4];
        float rm = -INFINITY;
#pragma unroll
        for (int nf = 0; nf < 4; ++nf)
#pragma unroll
            for (int r = 0; r < 4; ++r) {
                const int bit = nf * 16 + hi * 4 + r;
                const float svv = ((bits >> bit) & 1ull) ? s4t[nf][r] * 0.125f : NEGV;
                p[nf][r] = svv;
                rm = fmaxf(rm, svv);
            }
        rm = fmaxf(rm, __shfl_xor(rm, 16));
        rm = fmaxf(rm, __shfl_xor(rm, 32));
        const float mnew = fmaxf(mq, rm);
        const float corrq = __expf(mq - mnew);   // exp(-inf)=0 on iter 0
        float rs = 0.f;
#pragma unroll
        for (int nf = 0; nf < 4; ++nf)
#pragma unroll
            for (int r = 0; r < 4; ++r) {
                p[nf][r] = __expf(p[nf][r] - mnew);
                rs += p[nf][r];
            }
        rs += __shfl_xor(rs, 16);
        rs += __shfl_xor(rs, 32);
        lq = lq * corrq + rs;
        mq = mnew;

        // ---- P -> per-wave LDS [q][kpos] (same swizzle family as before) ----
#pragma unroll
        for (int nf = 0; nf < 4; ++nf)
#pragma unroll
            for (int r = 0; r < 4; ++r) {
                const int kpos = nf * 16 + hi * 4 + r;
                *(u16*)(smem + 16384 + w * 2048 + q * 128 +
                        ((kpos * 2) ^ ((q & 7) << 4))) = f2bf(p[nf][r]);
            }

        // ---- rescale oacc rows (corr from the lane owning that q-row) ----
#pragma unroll
        for (int r = 0; r < 4; ++r) {
            const float cr = __shfl(corrq, hi * 4 + r);
#pragma unroll
            for (int nf = 0; nf < 4; ++nf) oacc[nf][r] *= cr;
        }

        // ---- ctx += P V (unchanged) ----
#pragma unroll
        for (int ks = 0; ks < 2; ++ks) {
            const bf16x8 pf = *(const bf16x8*)(smem + 16384 + w * 2048 + q * 128 +
                    ((ks * 64 + hi * 16) ^ ((q & 7) << 4)));
#pragma unroll
            for (int nf = 0; nf < 4; ++nf) {
                const int vr = nf * 16 + q;
                const bf16x8 vf = *(const bf16x8*)(smem + 8192 + vr * 128 +
                        ((ks * 64 + hi * 16) ^ ((vr & 7) << 4)));
                oacc[nf] = __builtin_amdgcn_mfma_f32_16x16x32_bf16(pf, vf, oacc[nf], 0, 0, 0);
            }
        }
        // no trailing barrier: next iteration's pre-write barrier (plus the
        // compiler's pre-barrier waitcnt drain) protects Ks/Vs reads.
    }

    // ---- epilogue: ctx bf16, merged [B*S][HID] layout ----
#pragma unroll
    for (int r = 0; r < 4; ++r) {
        const float linv = 1.f / __shfl(lq, hi * 4 + r);
        const int srow = qt * 64 + w * 16 + hi * 4 + r;
#pragma unroll
        for (int nf = 0; nf < 4; ++nf) {
            const float v = oacc[nf][r] * linv;
            cb[((size_t)b * SLEN + srow) * HIDD + h * DHEAD + nf * 16 + q] = f2bf(v);
        }
    }
}

// ---------------------------------------------------------------------------
extern "C" void kernel_launch(void* const* d_in, const int* in_sizes, int n_in,
                              void* d_out, int out_size, void* d_ws, size_t ws_size,
                              hipStream_t stream)
{
    (void)in_sizes; (void)n_in; (void)out_size; (void)ws_size;
    const float* Q   = (const float*)d_in[0];
    const float* K   = (const float*)d_in[1];
    const float* V   = (const float*)d_in[2];
    const float* pad = (const float*)d_in[3];
    const float* am  = (const float*)d_in[4];
    const float* Wq  = (const float*)d_in[5];
    const float* bq  = (const float*)d_in[6];
    const float* Wk  = (const float*)d_in[7];
    const float* bk  = (const float*)d_in[8];
    const float* Wv  = (const float*)d_in[9];
    const float* bv  = (const float*)d_in[10];
    const float* Wo  = (const float*)d_in[11];
    const float* bo  = (const float*)d_in[12];
    float* out = (float*)d_out;

    char* ws = (char*)d_ws;
    const size_t MB = 1u << 20;
    u16* Qb  = (u16*)(ws + 0);        // 8MB (reused as cb after qkv)
    u16* Kb  = (u16*)(ws + 8  * MB);  // 8MB
    u16* Vb  = (u16*)(ws + 16 * MB);  // 8MB
    u16* Wqb = (u16*)(ws + 24 * MB);  // 2MB
    u16* Wkb = (u16*)(ws + 26 * MB);  // 2MB
    u16* Wvb = (u16*)(ws + 28 * MB);  // 2MB
    u16* Wob = (u16*)(ws + 30 * MB);  // 2MB
    u16* qhp = (u16*)(ws + 32 * MB);  // 8MB [B,NH,S,DH]
    u16* khp = (u16*)(ws + 40 * MB);  // 8MB
    u16* vhp = (u16*)(ws + 48 * MB);  // 8MB
    u16* vtp = (u16*)(ws + 56 * MB);  // 8MB [B,NH,DH,S]
    u64* mbp = (u64*)(ws + 64 * MB);  // 1MB mask bits
    u16* cbp = (u16*)(ws + 0);        // ctx bf16, aliases Qb (dead by then)

    cvt_kernel<<<dim3(2048, 1, 7), 256, 0, stream>>>(Q, K, V, Wq, Wk, Wv, Wo,
                                                     Qb, Kb, Vb, Wqb, Wkb, Wvb, Wob);
    qkv_kernel<<<dim3(8, 32, 3), 256, 0, stream>>>(Qb, Kb, Vb, Wqb, Wkb, Wvb,
                                                   bq, bk, bv, qhp, khp, vhp);
    vtrans_kernel<<<dim3(32, 32), 256, 0, stream>>>(vhp, vtp);
    mask_kernel<<<dim3(512), 256, 0, stream>>>(pad, am, mbp);
    flash_kernel<<<dim3(32, 16, 2), 256, 0, stream>>>(qhp, khp, vtp, mbp, cbp);
    outproj_kernel<<<dim3(8, 32, 1), 256, 0, stream>>>(cbp, Wob, bo, out);
}